// Round 8
// baseline (198.234 us; speedup 1.0000x reference)
//
#include <hip/hip_runtime.h>

#define KDIM 4096
#define NDIM 4096
#define BM 128
#define BN 256
#define BK 64             // K bytes (int8) per tile
#define NTILE (KDIM / BK) // 64
#define BUFSZ 24576       // A 128*64 + B 256*64
#define NBUF 3

using i32x4 = __attribute__((ext_vector_type(4))) int;

__device__ __forceinline__ void g2l16(const void* g, void* l) {
  __builtin_amdgcn_global_load_lds(
      (const __attribute__((address_space(1))) void*)g,
      (__attribute__((address_space(3))) void*)l,
      16, 0, 0);
}

// ---------------- detect: weight buffer int32-expanded (flag=1) or raw int8 (flag=0)?
__global__ void w8l_detect(const int* __restrict__ w32, int* __restrict__ flag) {
  __shared__ int s;
  const int t = threadIdx.x;
  if (t == 0) s = 1;
  __syncthreads();
  bool oob = false;
#pragma unroll
  for (int i = 0; i < 16; ++i) {
    int v = w32[t * 16 + i];
    if (v < -128 || v > 127) oob = true;
  }
  if (oob) atomicAnd(&s, 0);
  __syncthreads();
  if (t == 0) *flag = s;
}

// ---------------- pack int32 weights to int8 (no-op when flag==0)
__global__ void w8l_pack(const void* __restrict__ wsrc, const int* __restrict__ flag,
                         signed char* __restrict__ wq) {
  if (*flag == 0) return;
  const int t = blockIdx.x * blockDim.x + threadIdx.x;
  const int4* s = (const int4*)wsrc;
  int4 a = s[t * 4 + 0], b = s[t * 4 + 1], c = s[t * 4 + 2], d = s[t * 4 + 3];
  int4 o;
  o.x = (a.x & 255) | ((a.y & 255) << 8) | ((a.z & 255) << 16) | ((a.w & 255) << 24);
  o.y = (b.x & 255) | ((b.y & 255) << 8) | ((b.z & 255) << 16) | ((b.w & 255) << 24);
  o.z = (c.x & 255) | ((c.y & 255) << 8) | ((c.z & 255) << 16) | ((c.w & 255) << 24);
  o.w = (d.x & 255) | ((d.y & 255) << 8) | ((d.z & 255) << 16) | ((d.w & 255) << 24);
  ((int4*)wq)[t] = o;
}

// ---------------- quantize activations: 16 floats / thread
__global__ void w8l_quant(const float* __restrict__ x, const float* __restrict__ xs,
                          signed char* __restrict__ xq) {
  const int t = blockIdx.x * blockDim.x + threadIdx.x;
  const float s = *xs;
  const float4* x4 = (const float4*)x;
  int4 o;
  int* op = (int*)&o;
#pragma unroll
  for (int q = 0; q < 4; ++q) {
    float4 f = x4[t * 4 + q];
    int v0 = __float2int_rn(f.x / s);
    int v1 = __float2int_rn(f.y / s);
    int v2 = __float2int_rn(f.z / s);
    int v3 = __float2int_rn(f.w / s);
    v0 = v0 < -128 ? -128 : (v0 > 127 ? 127 : v0);
    v1 = v1 < -128 ? -128 : (v1 > 127 ? 127 : v1);
    v2 = v2 < -128 ? -128 : (v2 > 127 ? 127 : v2);
    v3 = v3 < -128 ? -128 : (v3 > 127 ? 127 : v3);
    op[q] = (v0 & 255) | ((v1 & 255) << 8) | ((v2 & 255) << 16) | ((v3 & 255) << 24);
  }
  ((int4*)xq)[t] = o;
}

// ---------------- 128x256 i8 GEMM, 4 waves/block, tri-buffered LDS (72 KiB)
// -> 2 blocks/CU: two independent barrier domains per CU; while one block
// drains vmcnt/barrier/lgkm, the other block's waves feed the MFMA pipe (m114).
// LDS buffer b at b*24576: A[128][64] at 0, B[256][64] at 8192.
// Row = 64 B = 4 slots of 16 B; LDS(r, c) holds global k-chunk (c ^ s(r)),
// s(r) = (r>>1)&3  => all frag reads <=2-way bank aliasing (free).
__global__ __launch_bounds__(256, 2) void w8l_gemm(
    const signed char* __restrict__ Aq,
    const signed char* __restrict__ Wraw, const signed char* __restrict__ Wpk,
    const int* __restrict__ flag,
    const float* __restrict__ scale, const float* __restrict__ xscale,
    const float* __restrict__ bias, float* __restrict__ out, int nbn) {
  __shared__ signed char lds[NBUF * BUFSZ];

  const signed char* __restrict__ Wq = (*flag) ? Wpk : Wraw;

  const int tid = threadIdx.x;
  const int lane = tid & 63;
  const int wid = tid >> 6;  // 0..3
  const int wr = wid >> 1;   // 0..1 (64-row half)
  const int wc = wid & 1;    // 0..1 (128-col half)
  const int l15 = lane & 15;
  const int l4 = (lane >> 4) & 3;  // k-quarter

  // XCD-aware bijective swizzle (grid = 1024, divisible by 8)
  const int nwg = gridDim.x;
  const int cpx = nwg >> 3;
  const int bid = blockIdx.x;
  const int swz = (bid & 7) * cpx + (bid >> 3);
  const int bm = swz / nbn, bn = swz % nbn;
  const int m0 = bm * BM, n0 = bn * BN;

  // staging: one g2l16 issue = 256 thr x 16 B = 4 KB = 64 rows x 64 B.
  // source column pre-swizzled; s(r) invariant under r += 64.
  const unsigned r_in = (unsigned)tid >> 2;       // 0..63
  const unsigned c16 = (unsigned)tid & 3;         // slot
  const unsigned s_in = (r_in >> 1) & 3u;
  const unsigned swcol = ((c16 ^ s_in) << 4);
  const signed char* agp = Aq + (size_t)(m0 + r_in) * KDIM + swcol;
  const signed char* wgp = Wq + (size_t)(n0 + r_in) * KDIM + swcol;
  const unsigned ldsoff = (unsigned)tid * 16u;    // linear dest (wave base + lane*16)

#define ISSUE_TILE(t, buf)                                                   \
  do {                                                                       \
    const size_t koff_ = (size_t)(t) * BK;                                   \
    signed char* lb_ = lds + (unsigned)(buf) * BUFSZ + ldsoff;               \
    _Pragma("unroll") for (int u = 0; u < 2; ++u)                            \
      g2l16(agp + (size_t)(u * 64) * KDIM + koff_, lb_ + u * 4096);          \
    _Pragma("unroll") for (int u = 0; u < 4; ++u)                            \
      g2l16(wgp + (size_t)(u * 64) * KDIM + koff_, lb_ + 8192 + u * 4096);   \
  } while (0)

  // per-lane read constants: frag(row base R): addr = R*64 + l15*64 + slotoff
  // s(R+l15) = (l15>>1)&3 because all R are multiples of 16.
  const unsigned slotoff = (unsigned)((l4 ^ ((l15 >> 1) & 3)) << 4);
  const unsigned arow = (unsigned)((wr * 64 + l15) * 64) + slotoff;
  const unsigned brow = (unsigned)((wc * 128 + l15) * 64) + slotoff + 8192u;

  i32x4 acc[4][8] = {};
  i32x4 af[4], bf[8];

  ISSUE_TILE(0, 0);
  ISSUE_TILE(1, 1);

  int bufr = 0, bufi = 2;
#pragma unroll 1
  for (int kt = 0; kt < NTILE; ++kt) {
    // own g2l(kt) landed (6 of tile kt+1 stay in flight); then block-wide sync
    if (kt + 2 < NTILE) {
      asm volatile("s_waitcnt vmcnt(6)" ::: "memory");
    } else {
      asm volatile("s_waitcnt vmcnt(0)" ::: "memory");
    }
    __builtin_amdgcn_s_barrier();
    __builtin_amdgcn_sched_barrier(0);

    // stage kt+2 into buf (kt+2)%3: WAR-safe — its last readers (tile kt-1)
    // drained via their lgkmcnt(0) before reaching the barrier above.
    if (kt + 2 < NTILE) ISSUE_TILE(kt + 2, bufi);

    const signed char* base = lds + (unsigned)bufr * BUFSZ;
#pragma unroll
    for (int mi = 0; mi < 4; ++mi)
      af[mi] = *(const i32x4*)(base + arow + mi * 1024);
#pragma unroll
    for (int nj = 0; nj < 8; ++nj)
      bf[nj] = *(const i32x4*)(base + brow + nj * 1024);
    __builtin_amdgcn_sched_barrier(0);
    asm volatile("s_waitcnt lgkmcnt(0)" ::: "memory");
    __builtin_amdgcn_sched_barrier(0);

    __builtin_amdgcn_s_setprio(1);
#pragma unroll
    for (int mi = 0; mi < 4; ++mi)
#pragma unroll
      for (int nj = 0; nj < 8; ++nj)
        acc[mi][nj] = __builtin_amdgcn_mfma_i32_16x16x64_i8(af[mi], bf[nj], acc[mi][nj], 0, 0, 0);
    __builtin_amdgcn_s_setprio(0);
    __builtin_amdgcn_sched_barrier(0);

    bufr = (bufr == 2) ? 0 : bufr + 1;
    bufi = (bufi == 2) ? 0 : bufi + 1;
  }

  // epilogue: C/D layout col=lane&15, row=(lane>>4)*4+reg [m89, dtype-indep]
  const float cs = scale[0] * xscale[0];
#pragma unroll
  for (int nj = 0; nj < 8; ++nj) {
    const int n = n0 + wc * 128 + nj * 16 + l15;
    const float bj = bias[n];
#pragma unroll
    for (int mi = 0; mi < 4; ++mi) {
      const int m = m0 + wr * 64 + mi * 16 + l4 * 4;
      float* o = out + (size_t)m * NDIM + n;
#pragma unroll
      for (int v = 0; v < 4; ++v)
        o[(size_t)v * NDIM] = (float)acc[mi][nj][v] * cs + bj;
    }
  }
#undef ISSUE_TILE
}

extern "C" void kernel_launch(void* const* d_in, const int* in_sizes, int n_in,
                              void* d_out, int out_size, void* d_ws, size_t ws_size,
                              hipStream_t stream) {
  const float* x = (const float*)d_in[0];
  const void* w = d_in[1];
  const float* scale = (const float*)d_in[2];
  const float* xscale = (const float*)d_in[3];
  const float* bias = (const float*)d_in[4];
  float* out = (float*)d_out;

  const int M = in_sizes[0] / KDIM;  // 8192

  int* flag = (int*)d_ws;
  signed char* wq = (signed char*)d_ws + 256;
  signed char* aq = wq + (size_t)NDIM * KDIM;

  const size_t need = 256 + (size_t)NDIM * KDIM + (size_t)M * KDIM;
  if (ws_size < need) return;

  w8l_detect<<<1, 256, 0, stream>>>((const int*)w, flag);
  w8l_pack<<<(NDIM * KDIM / 16) / 256, 256, 0, stream>>>(w, flag, wq);
  w8l_quant<<<(M * KDIM / 16) / 256, 256, 0, stream>>>(x, xscale, aq);

  const int nbn = NDIM / BN;  // 16
  w8l_gemm<<<(M / BM) * nbn, 256, 0, stream>>>(
      aq, (const signed char*)w, wq, flag, scale, xscale, bias, out, nbn);
}